// Round 3
// baseline (8105.424 us; speedup 1.0000x reference)
//
#include <hip/hip_runtime.h>
#include <hip/hip_bf16.h>

// Problem dims
#define T_STEPS 2048
#define BATCH   256
#define INW     64
#define H1      1280
#define H4D     320
#define H8D     160
#define G4      640   // 4*H8
#define ONUM    32

typedef __attribute__((ext_vector_type(8))) short short8;   // 8 x bf16
typedef __attribute__((ext_vector_type(4))) float floatx4;
typedef __hip_bfloat16 bf16;

__device__ __forceinline__ float b2f(bf16 v) { return __bfloat162float(v); }
__device__ __forceinline__ bf16  f2b(float v) { return __float2bfloat16(v); }
__device__ __forceinline__ float fsig(float x)  { return __fdividef(1.0f, 1.0f + __expf(-x)); }
__device__ __forceinline__ float ftanh(float x) { return __fdividef(2.0f, 1.0f + __expf(-2.0f * x)) - 1.0f; }

// ---------------- cast fp32 -> bf16 (vectorized x4) ----------------
struct bf16x4 { bf16 a, b, c, d; };
__global__ void cast_f32_bf16_v4(const float* __restrict__ s, bf16* __restrict__ d, int n4) {
  int i = blockIdx.x * blockDim.x + threadIdx.x;
  if (i >= n4) return;
  float4 v = reinterpret_cast<const float4*>(s)[i];
  bf16x4 o{f2b(v.x), f2b(v.y), f2b(v.z), f2b(v.w)};
  reinterpret_cast<bf16x4*>(d)[i] = o;
}

// ---------------- GEMM: C = act(A[M,K] @ W[N,K]^T + bias) ----------------
// 64x64 tile, 256 threads (4 waves, 2x2 wave grid of 32x32), BK=64, bf16 in.
// ACT: 1 = leaky_relu(0.01)+bias, bf16 out (Cb)
//      2 = gate-interleaved f32 out: Cf[row][ix*4+g], bias+bias2 folded
template <int ACT>
__global__ __launch_bounds__(256) void gemm_bt(
    const bf16* __restrict__ A, const bf16* __restrict__ W,
    const float* __restrict__ bias, const float* __restrict__ bias2,
    bf16* __restrict__ Cb, float* __restrict__ Cf, int M, int N, int K)
{
  __shared__ __align__(16) bf16 As[64][72];   // +8 pad: 16B-aligned rows, banks spread
  __shared__ __align__(16) bf16 Ws[64][72];
  const int tid  = threadIdx.x;
  const int lane = tid & 63;
  const int wave = tid >> 6;
  const int mrow = lane & 15;
  const int quad = lane >> 4;
  const int bm = blockIdx.x * 64;
  const int bn = blockIdx.y * 64;
  const int wm = (wave >> 1) * 32;
  const int wn = (wave & 1) * 32;
  const int lr = tid >> 2;  // staging row 0..63
  const int ls = tid & 3;   // staging segment

  floatx4 acc[2][2] = {};

  for (int k0 = 0; k0 < K; k0 += 64) {
    short8 a0 = *reinterpret_cast<const short8*>(&A[(size_t)(bm + lr) * K + k0 + ls * 8]);
    short8 a1 = *reinterpret_cast<const short8*>(&A[(size_t)(bm + lr) * K + k0 + ls * 8 + 32]);
    short8 w0 = *reinterpret_cast<const short8*>(&W[(size_t)(bn + lr) * K + k0 + ls * 8]);
    short8 w1 = *reinterpret_cast<const short8*>(&W[(size_t)(bn + lr) * K + k0 + ls * 8 + 32]);
    __syncthreads();
    *reinterpret_cast<short8*>(&As[lr][ls * 8])      = a0;
    *reinterpret_cast<short8*>(&As[lr][ls * 8 + 32]) = a1;
    *reinterpret_cast<short8*>(&Ws[lr][ls * 8])      = w0;
    *reinterpret_cast<short8*>(&Ws[lr][ls * 8 + 32]) = w1;
    __syncthreads();
#pragma unroll
    for (int kk = 0; kk < 2; ++kk) {
      short8 af0 = *reinterpret_cast<const short8*>(&As[wm + mrow][kk * 32 + quad * 8]);
      short8 af1 = *reinterpret_cast<const short8*>(&As[wm + 16 + mrow][kk * 32 + quad * 8]);
      short8 wf0 = *reinterpret_cast<const short8*>(&Ws[wn + mrow][kk * 32 + quad * 8]);
      short8 wf1 = *reinterpret_cast<const short8*>(&Ws[wn + 16 + mrow][kk * 32 + quad * 8]);
      acc[0][0] = __builtin_amdgcn_mfma_f32_16x16x32_bf16(af0, wf0, acc[0][0], 0, 0, 0);
      acc[0][1] = __builtin_amdgcn_mfma_f32_16x16x32_bf16(af0, wf1, acc[0][1], 0, 0, 0);
      acc[1][0] = __builtin_amdgcn_mfma_f32_16x16x32_bf16(af1, wf0, acc[1][0], 0, 0, 0);
      acc[1][1] = __builtin_amdgcn_mfma_f32_16x16x32_bf16(af1, wf1, acc[1][1], 0, 0, 0);
    }
  }
#pragma unroll
  for (int i = 0; i < 2; ++i) {
#pragma unroll
    for (int j = 0; j < 2; ++j) {
      int col = bn + wn + j * 16 + mrow;
      float bv = 0.0f;
      if (ACT == 1) bv = bias[col];
      if (ACT == 2) bv = bias[col] + bias2[col];
      int g = 0, ix = 0;
      if (ACT == 2) { g = col / 160; ix = col - g * 160; }
#pragma unroll
      for (int r = 0; r < 4; ++r) {
        int row = bm + wm + i * 16 + quad * 4 + r;
        float v = acc[i][j][r] + bv;
        if (ACT == 1) {
          v = (v > 0.0f) ? v : 0.01f * v;
          Cb[(size_t)row * N + col] = f2b(v);
        } else {
          Cf[(size_t)row * 640 + ix * 4 + g] = v;
        }
      }
    }
  }
}

// ---------------- recurrent kernel ----------------
// 16 blocks x 640 threads (10 waves), block b owns batch rows [16b,16b+16).
// Wave w owns ix columns [16w,16w+16), i.e. Whh output tiles {w,10+w,20+w,30+w}
// so each lane's acc[4] holds ALL FOUR gates of its 4 (row,ix) cells ->
// elementwise fully in registers (c in VGPRs), no gates LDS round-trip.
// h tile double-buffered in LDS -> ONE barrier per step.
// y_t = h_t @ W3^T computed at iteration t+1 reusing the af fragments.
__global__ __launch_bounds__(640, 1) void recur_kernel(
    const float* __restrict__ gx,     // [Tc*256][160][4] f32, biases folded
    const bf16* __restrict__ Whh,     // [640,160] bf16
    const bf16* __restrict__ W3w,     // [32,160]  bf16
    const float* __restrict__ b3,
    bf16* __restrict__ h_ws,          // [256,160] bf16 (persist across chunks)
    float* __restrict__ c_ws,         // [256,160] f32
    float* __restrict__ outp,         // out + chunk offset: [Tc*256*32]
    int Tc, int init)
{
  __shared__ __align__(16) bf16 hbuf[2][16][168];  // double-buffered h tile
  __shared__ __align__(16) bf16 w3s[32][168];
  const int tid  = threadIdx.x;
  const int lane = tid & 63;
  const int wave = tid >> 6;    // 0..9
  const int mrow = lane & 15;
  const int quad = lane >> 4;
  const int bbase = blockIdx.x * 16;
  const int ixg = wave * 16 + mrow;   // this lane's ix column

  // W_hh fragments in registers: 4 gates x 5 k-steps = 80 VGPRs/lane
  short8 whf[4][5];
#pragma unroll
  for (int g = 0; g < 4; ++g)
#pragma unroll
    for (int ks = 0; ks < 5; ++ks)
      whf[g][ks] = *reinterpret_cast<const short8*>(
          &Whh[(size_t)(g * 160 + ixg) * 160 + ks * 32 + quad * 8]);

  // W3 into LDS (read per-iter by waves 0,1)
  for (int e = tid; e < 32 * 160; e += 640) {
    int r = e / 160, cix = e - r * 160;
    w3s[r][cix] = W3w[e];
  }
  const float b3v = (wave < 2) ? b3[wave * 16 + mrow] : 0.0f;

  // c state in registers; h into hbuf[0]
  float c[4];
#pragma unroll
  for (int r = 0; r < 4; ++r)
    c[r] = init ? 0.0f : c_ws[(size_t)(bbase + quad * 4 + r) * 160 + ixg];
  for (int e = tid; e < 16 * 160; e += 640) {
    int r = e / 160, cix = e - r * 160;
    hbuf[0][r][cix] = init ? f2b(0.0f) : h_ws[(size_t)(bbase + r) * 160 + cix];
  }
  __syncthreads();

  const float4* __restrict__ gxp = reinterpret_cast<const float4*>(gx);
  size_t goff[4];
#pragma unroll
  for (int r = 0; r < 4; ++r)
    goff[r] = (size_t)(bbase + quad * 4 + r) * 160 + ixg;

  for (int t = 0; t < Tc; ++t) {
    const int rb = t & 1, wb = rb ^ 1;

    // h fragments (A-operand) from current buffer
    short8 af[5];
#pragma unroll
    for (int ks = 0; ks < 5; ++ks)
      af[ks] = *reinterpret_cast<const short8*>(&hbuf[rb][mrow][ks * 32 + quad * 8]);

    // issue this step's gx loads early (latency covered by MFMA phase)
    float4 gv[4];
    {
      size_t tb = (size_t)t * (256 * 160);
#pragma unroll
      for (int r = 0; r < 4; ++r) gv[r] = gxp[tb + goff[r]];
    }

    // y for step t-1 (af == h_{t-1} fragments), waves 0,1
    if (wave < 2 && t > 0) {
      short8 w3f[5];
#pragma unroll
      for (int ks = 0; ks < 5; ++ks)
        w3f[ks] = *reinterpret_cast<const short8*>(&w3s[wave * 16 + mrow][ks * 32 + quad * 8]);
      floatx4 ya = {};
#pragma unroll
      for (int ks = 0; ks < 5; ++ks)
        ya = __builtin_amdgcn_mfma_f32_16x16x32_bf16(af[ks], w3f[ks], ya, 0, 0, 0);
      float* op = outp + ((size_t)(t - 1) * 256 + bbase) * 32 + wave * 16 + mrow;
#pragma unroll
      for (int r = 0; r < 4; ++r)
        op[(size_t)(quad * 4 + r) * 32] = ya[r] + b3v;
    }

    // hh MFMA: acc[g][r] = gate_g[row=quad*4+r][ix=ixg]
    floatx4 acc[4] = {};
#pragma unroll
    for (int ks = 0; ks < 5; ++ks)
#pragma unroll
      for (int g = 0; g < 4; ++g)
        acc[g] = __builtin_amdgcn_mfma_f32_16x16x32_bf16(af[ks], whf[g][ks], acc[g], 0, 0, 0);

    // LSTM cell, fully in registers
#pragma unroll
    for (int r = 0; r < 4; ++r) {
      float xi = acc[0][r] + gv[r].x;
      float xf = acc[1][r] + gv[r].y;
      float xg = acc[2][r] + gv[r].z;
      float xo = acc[3][r] + gv[r].w;
      float iv = fsig(xi), fv = fsig(xf), gvv = ftanh(xg), ov = fsig(xo);
      float cv = fv * c[r] + iv * gvv;
      c[r] = cv;
      hbuf[wb][quad * 4 + r][ixg] = f2b(ov * ftanh(cv));
    }
    __syncthreads();
  }

  // final y for step Tc-1
  if (wave < 2) {
    const int rb = Tc & 1;
    short8 af[5], w3f[5];
#pragma unroll
    for (int ks = 0; ks < 5; ++ks) {
      af[ks]  = *reinterpret_cast<const short8*>(&hbuf[rb][mrow][ks * 32 + quad * 8]);
      w3f[ks] = *reinterpret_cast<const short8*>(&w3s[wave * 16 + mrow][ks * 32 + quad * 8]);
    }
    floatx4 ya = {};
#pragma unroll
    for (int ks = 0; ks < 5; ++ks)
      ya = __builtin_amdgcn_mfma_f32_16x16x32_bf16(af[ks], w3f[ks], ya, 0, 0, 0);
    float* op = outp + ((size_t)(Tc - 1) * 256 + bbase) * 32 + wave * 16 + mrow;
#pragma unroll
    for (int r = 0; r < 4; ++r)
      op[(size_t)(quad * 4 + r) * 32] = ya[r] + b3v;
  }

  // persist state
  for (int e = tid; e < 16 * 160; e += 640) {
    int r = e / 160, cix = e - r * 160;
    h_ws[(size_t)(bbase + r) * 160 + cix] = hbuf[Tc & 1][r][cix];
  }
#pragma unroll
  for (int r = 0; r < 4; ++r)
    c_ws[(size_t)(bbase + quad * 4 + r) * 160 + ixg] = c[r];
}

// ---------------- launch ----------------
extern "C" void kernel_launch(void* const* d_in, const int* in_sizes, int n_in,
                              void* d_out, int out_size, void* d_ws, size_t ws_size,
                              hipStream_t stream)
{
  const float* inp = (const float*)d_in[0];
  const float* W1  = (const float*)d_in[1];
  const float* b1  = (const float*)d_in[2];
  const float* W2  = (const float*)d_in[3];
  const float* b2  = (const float*)d_in[4];
  const float* Wih = (const float*)d_in[5];
  const float* Whh = (const float*)d_in[6];
  const float* bih = (const float*)d_in[7];
  const float* bhh = (const float*)d_in[8];
  const float* W3  = (const float*)d_in[9];
  const float* b3  = (const float*)d_in[10];
  float* out = (float*)d_out;

  char* ws = (char*)d_ws;
  size_t off = 0;
  auto alloc = [&](size_t bytes) -> char* {
    char* p = ws + off;
    off += (bytes + 255) & ~(size_t)255;
    return p;
  };

  bf16* inpb = (bf16*)alloc((size_t)T_STEPS * BATCH * INW * 2);
  bf16* w1b  = (bf16*)alloc((size_t)H1 * INW * 2);
  bf16* w2b  = (bf16*)alloc((size_t)H4D * H1 * 2);
  bf16* wihb = (bf16*)alloc((size_t)G4 * H4D * 2);
  bf16* whhb = (bf16*)alloc((size_t)G4 * H8D * 2);
  bf16* w3b  = (bf16*)alloc((size_t)ONUM * H8D * 2);
  bf16* h_ws = (bf16*)alloc((size_t)BATCH * H8D * 2);
  float* c_ws = (float*)alloc((size_t)BATCH * H8D * 4);
  size_t fixed = off;

  int Tc = 128;  // time chunk; shrink if workspace is small
  while (Tc > 16) {
    size_t Mc = (size_t)Tc * BATCH;
    size_t need = fixed
      + ((Mc * H1 * 2 + 255) & ~(size_t)255)
      + ((Mc * H4D * 2 + 255) & ~(size_t)255)
      + ((Mc * G4 * 4 + 255) & ~(size_t)255);   // gx is f32 now
    if (need <= ws_size) break;
    Tc >>= 1;
  }
  const size_t Mc = (size_t)Tc * BATCH;
  bf16*  x2 = (bf16*)alloc(Mc * H1 * 2);
  bf16*  x4 = (bf16*)alloc(Mc * H4D * 2);
  float* gx = (float*)alloc(Mc * G4 * 4);

  // casts (done every call; harness re-poisons ws before each timed launch)
  {
    int n4 = T_STEPS * BATCH * INW / 4;
    cast_f32_bf16_v4<<<(n4 + 255) / 256, 256, 0, stream>>>(inp, inpb, n4);
    n4 = H1 * INW / 4;
    cast_f32_bf16_v4<<<(n4 + 255) / 256, 256, 0, stream>>>(W1, w1b, n4);
    n4 = H4D * H1 / 4;
    cast_f32_bf16_v4<<<(n4 + 255) / 256, 256, 0, stream>>>(W2, w2b, n4);
    n4 = G4 * H4D / 4;
    cast_f32_bf16_v4<<<(n4 + 255) / 256, 256, 0, stream>>>(Wih, wihb, n4);
    n4 = G4 * H8D / 4;
    cast_f32_bf16_v4<<<(n4 + 255) / 256, 256, 0, stream>>>(Whh, whhb, n4);
    n4 = ONUM * H8D / 4;
    cast_f32_bf16_v4<<<(n4 + 255) / 256, 256, 0, stream>>>(W3, w3b, n4);
  }

  const int nchunks = T_STEPS / Tc;
  for (int ch = 0; ch < nchunks; ++ch) {
    const bf16* Ain = inpb + (size_t)ch * Mc * INW;
    gemm_bt<1><<<dim3((unsigned)(Mc / 64), H1 / 64), 256, 0, stream>>>(
        Ain, w1b, b1, nullptr, x2, nullptr, (int)Mc, H1, INW);
    gemm_bt<1><<<dim3((unsigned)(Mc / 64), H4D / 64), 256, 0, stream>>>(
        x2, w2b, b2, nullptr, x4, nullptr, (int)Mc, H4D, H1);
    gemm_bt<2><<<dim3((unsigned)(Mc / 64), G4 / 64), 256, 0, stream>>>(
        x4, wihb, bih, bhh, nullptr, gx, (int)Mc, G4, H4D);
    recur_kernel<<<16, 640, 0, stream>>>(
        gx, whhb, w3b, b3, h_ws, c_ws,
        out + (size_t)ch * Tc * BATCH * ONUM, Tc, ch == 0 ? 1 : 0);
  }
}